// Round 14
// baseline (276.669 us; speedup 1.0000x reference)
//
#include <hip/hip_runtime.h>

#define LUT_N 4096
#define DVAL  4096
#define TPB   256

static constexpr double TWO_PI_D = 6.283185307179586476925286766559;
#define PHI_F 1.61803398874989484820f

// ---------- helpers ----------
__device__ __forceinline__ float fc(const float4& f, int j) {
    switch (j) { case 0: return f.x; case 1: return f.y; case 2: return f.z; }
    return f.w;
}
__device__ __forceinline__ void sc4(float4& f, int j, float v) {
    switch (j) { case 0: f.x = v; return; case 1: f.y = v; return; case 2: f.z = v; return; }
    f.w = v;
}
// Reference: idx = mod(round(theta*(N/2pi)), N); value = table[idx].
// Same quantization (rintf = round-half-even = jnp.round), value via HW trans ops
// (input in REVOLUTIONS): sin/cos(2*pi*fract((r+s)/4096)). |r+s| < 2^24 so the mod
// is exact; argument error <= 5e-7 << validated 0.0039 absmax.
__device__ __forceinline__ void grid_sincos(float thr, float thi, float cidx,
                                            float& s_out, float& c_out) {
    float r = rintf(thr * cidx);
    float s = rintf(thi * cidx);
    float rev = (r + s) * (1.0f / (float)LUT_N);
    float frac = rev - floorf(rev);
    s_out = __builtin_amdgcn_sinf(frac);
    c_out = __builtin_amdgcn_cosf(frac);
}

// ---------- precompute: per-column reciprocals ----------
__global__ __launch_bounds__(256) void echo_precompute(
    const float* __restrict__ w_query,
    const float* __restrict__ w_out,
    const float* __restrict__ beta,
    float* __restrict__ invq,  // [D] 1/(1+|w_query|)
    float* __restrict__ wsi)   // [D] write_scale/wavelength
{
    int i = blockIdx.x * 256 + threadIdx.x;
    if (i < DVAL) {
        float inv_q     = 1.0f / (1.0f + fabsf(w_query[i]));
        float w_eff     = 1.0f / (1.0f + fabsf(w_out[i]));
        float beta_eff  = 1.0f / (1.0f + fabsf(beta[i]));
        float decay     = fminf(expf(-beta_eff * w_eff), 0.9999f);
        invq[i] = inv_q;
        wsi[i]  = (w_eff * (1.0f - decay)) * w_eff;
    }
}

// ---------- K1: per-row interference magnitude (reduction only) ----------
__global__ __launch_bounds__(TPB) void echo_mag(
    const float* __restrict__ x_real,
    const float* __restrict__ x_imag,
    const float* __restrict__ t,
    const float* __restrict__ trig_r,
    const float* __restrict__ trig_i,
    const float* __restrict__ b_query,
    const float* __restrict__ invqG,
    float* __restrict__ magG)          // [B] output
{
    __shared__ float redR[4], redI[4];

    const int tid = threadIdx.x;
    const int row = blockIdx.x;
    const float cidx = (float)((double)LUT_N / TWO_PI_D);

    const float tphi = t[row] * PHI_F;
    const float* xr = x_real + (size_t)row * DVAL;
    const float* xi = x_imag + (size_t)row * DVAL;

    float accr = 0.0f, acci = 0.0f;

    #pragma unroll
    for (int k = 0; k < 4; ++k) {
        int v = tid + TPB * k;
        float4 a   = ((const float4*)xr)[v];
        float4 c   = ((const float4*)xi)[v];
        float4 iv4 = ((const float4*)invqG)[v];
        float4 bq4 = ((const float4*)b_query)[v];
        float4 tr4 = ((const float4*)trig_r)[v];
        float4 ti4 = ((const float4*)trig_i)[v];

        #pragma unroll
        for (int j = 0; j < 4; ++j) {
            float iv = fc(iv4, j), bq = fc(bq4, j);
            float thr = __builtin_fmaf(fc(a, j), iv, bq) + tphi;
            float thi = __builtin_fmaf(fc(c, j), iv, bq) + tphi;
            float q_i, q_r;
            grid_sincos(thr, thi, cidx, q_i, q_r);
            accr = __builtin_fmaf(q_r, fc(tr4, j), __builtin_fmaf(q_i, fc(ti4, j), accr));
            acci = __builtin_fmaf(q_r, fc(ti4, j), __builtin_fmaf(-q_i, fc(tr4, j), acci));
        }
    }

    #pragma unroll
    for (int m = 32; m >= 1; m >>= 1) {
        accr += __shfl_xor(accr, m, 64);
        acci += __shfl_xor(acci, m, 64);
    }
    if ((tid & 63) == 0) { redR[tid >> 6] = accr; redI[tid >> 6] = acci; }
    __syncthreads();
    if (tid == 0) {
        float tr = (redR[0] + redR[1] + redR[2] + redR[3]) * 0.0625f;
        float ti = (redI[0] + redI[1] + redI[2] + redI[3]) * 0.0625f;
        magG[row] = sqrtf(tr * tr + ti * ti + 1e-8f);
    }
}

// ---------- K2: pure grid-stride projection (memcpy-shaped, no barriers) ----------
__global__ __launch_bounds__(TPB, 4) void echo_proj(
    const float* __restrict__ x_real,
    const float* __restrict__ x_imag,
    const float* __restrict__ t,
    const float* __restrict__ b_out,
    const float* __restrict__ wsiG,
    const float* __restrict__ magG,
    float* __restrict__ out,
    int B, int nblocks)
{
    const float cidx = (float)((double)LUT_N / TWO_PI_D);
    const int nvec_row = DVAL / 4;                    // 1024 float4 per row
    const long total   = (long)B * nvec_row;          // 4M float4 per array
    const long stride  = (long)nblocks * TPB;
    long g = (long)blockIdx.x * TPB + threadIdx.x;

    const float4* xr4 = (const float4*)x_real;
    const float4* xi4 = (const float4*)x_imag;
    const float4* bo4G = (const float4*)b_out;
    const float4* ws4G = (const float4*)wsiG;
    float4* outR = (float4*)out;
    float4* outI = (float4*)(out + (size_t)B * DVAL);

    #pragma unroll 4
    for (long i = g; i < total; i += stride) {
        int row  = (int)(i >> 10);                    // i / 1024
        int col4 = (int)(i & 1023);

        float4 a   = xr4[i];
        float4 c   = xi4[i];
        float4 ws4 = ws4G[col4];
        float4 bo  = bo4G[col4];
        float mag  = magG[row];
        float tphi = t[row] * PHI_F;

        float4 oR, oI;
        #pragma unroll
        for (int j = 0; j < 4; ++j) {
            float xmr = fc(a, j) * mag;
            float xmi = fc(c, j) * mag;
            float thr = __builtin_fmaf(xmr, fc(ws4, j), fc(bo, j)) + tphi;
            float thi = __builtin_fmaf(xmi, fc(ws4, j), fc(bo, j)) + tphi;
            float s_o, c_o;
            grid_sincos(thr, thi, cidx, s_o, c_o);
            sc4(oR, j, c_o);
            sc4(oI, j, s_o);
        }
        outR[i] = oR;
        outI[i] = oI;
    }
}

// ---------- fallback single kernel (no workspace): r13-validated path ----------
__global__ __launch_bounds__(TPB, 4) void echo_single(
    const float* __restrict__ x_real,
    const float* __restrict__ x_imag,
    const float* __restrict__ t,
    const float* __restrict__ trig_r,
    const float* __restrict__ trig_i,
    const float* __restrict__ w_query,
    const float* __restrict__ b_query,
    const float* __restrict__ w_out,
    const float* __restrict__ b_out,
    const float* __restrict__ beta,
    float* __restrict__ out,
    int B)
{
    __shared__ float redR[4], redI[4];
    __shared__ float magS;

    const int tid = threadIdx.x;
    const int row = blockIdx.x;
    const float cidx = (float)((double)LUT_N / TWO_PI_D);

    const float tphi = t[row] * PHI_F;
    const float* xr = x_real + (size_t)row * DVAL;
    const float* xi = x_imag + (size_t)row * DVAL;

    float4 xr_s[4], xi_s[4];
    float accr = 0.0f, acci = 0.0f;

    #pragma unroll
    for (int k = 0; k < 4; ++k) {
        int v = tid + TPB * k;
        float4 a = ((const float4*)xr)[v];
        float4 c = ((const float4*)xi)[v];
        xr_s[k] = a; xi_s[k] = c;
        float4 wq4 = ((const float4*)w_query)[v];
        float4 iv4 = make_float4(1.0f / (1.0f + fabsf(wq4.x)), 1.0f / (1.0f + fabsf(wq4.y)),
                                 1.0f / (1.0f + fabsf(wq4.z)), 1.0f / (1.0f + fabsf(wq4.w)));
        float4 bq4 = ((const float4*)b_query)[v];
        float4 tr4 = ((const float4*)trig_r)[v];
        float4 ti4 = ((const float4*)trig_i)[v];
        #pragma unroll
        for (int j = 0; j < 4; ++j) {
            float iv = fc(iv4, j), bq = fc(bq4, j);
            float thr = __builtin_fmaf(fc(a, j), iv, bq) + tphi;
            float thi = __builtin_fmaf(fc(c, j), iv, bq) + tphi;
            float q_i, q_r;
            grid_sincos(thr, thi, cidx, q_i, q_r);
            accr = __builtin_fmaf(q_r, fc(tr4, j), __builtin_fmaf(q_i, fc(ti4, j), accr));
            acci = __builtin_fmaf(q_r, fc(ti4, j), __builtin_fmaf(-q_i, fc(tr4, j), acci));
        }
    }
    #pragma unroll
    for (int m = 32; m >= 1; m >>= 1) {
        accr += __shfl_xor(accr, m, 64);
        acci += __shfl_xor(acci, m, 64);
    }
    if ((tid & 63) == 0) { redR[tid >> 6] = accr; redI[tid >> 6] = acci; }
    __syncthreads();
    if (tid == 0) {
        float tr = (redR[0] + redR[1] + redR[2] + redR[3]) * 0.0625f;
        float ti = (redI[0] + redI[1] + redI[2] + redI[3]) * 0.0625f;
        magS = sqrtf(tr * tr + ti * ti + 1e-8f);
    }
    __syncthreads();
    const float mag = magS;

    float4* outR = (float4*)(out + (size_t)row * DVAL);
    float4* outI = (float4*)(out + (size_t)B * DVAL + (size_t)row * DVAL);
    #pragma unroll
    for (int k = 0; k < 4; ++k) {
        int v = tid + TPB * k;
        float4 wo4 = ((const float4*)w_out)[v];
        float4 be4 = ((const float4*)beta)[v];
        float4 ws4;
        #pragma unroll
        for (int j = 0; j < 4; ++j) {
            float w_eff = 1.0f / (1.0f + fabsf(fc(wo4, j)));
            float beta_eff = 1.0f / (1.0f + fabsf(fc(be4, j)));
            float decay = fminf(expf(-beta_eff * w_eff), 0.9999f);
            sc4(ws4, j, (w_eff * (1.0f - decay)) * w_eff);
        }
        float4 bo4 = ((const float4*)b_out)[v];
        float4 oR, oI;
        #pragma unroll
        for (int j = 0; j < 4; ++j) {
            float xmr = fc(xr_s[k], j) * mag;
            float xmi = fc(xi_s[k], j) * mag;
            float thr = __builtin_fmaf(xmr, fc(ws4, j), fc(bo4, j)) + tphi;
            float thi = __builtin_fmaf(xmi, fc(ws4, j), fc(bo4, j)) + tphi;
            float s_o, c_o;
            grid_sincos(thr, thi, cidx, s_o, c_o);
            sc4(oR, j, c_o);
            sc4(oI, j, s_o);
        }
        outR[v] = oR;
        outI[v] = oI;
    }
}

extern "C" void kernel_launch(void* const* d_in, const int* in_sizes, int n_in,
                              void* d_out, int out_size, void* d_ws, size_t ws_size,
                              hipStream_t stream) {
    const float* x_real    = (const float*)d_in[0];
    const float* x_imag    = (const float*)d_in[1];
    const float* t         = (const float*)d_in[2];
    const float* trig_r    = (const float*)d_in[3];
    const float* trig_i    = (const float*)d_in[4];
    const float* w_query   = (const float*)d_in[5];
    const float* b_query   = (const float*)d_in[6];
    const float* w_out     = (const float*)d_in[7];
    const float* b_out     = (const float*)d_in[8];
    const float* beta      = (const float*)d_in[9];
    float* out = (float*)d_out;

    const int B = in_sizes[2];          // 4096
    const size_t need = (2 * (size_t)DVAL + (size_t)B) * sizeof(float);

    if (d_ws != nullptr && ws_size >= need) {
        float* invq = (float*)d_ws;
        float* wsi  = invq + DVAL;
        float* mag  = wsi + DVAL;
        echo_precompute<<<DVAL / 256, 256, 0, stream>>>(w_query, w_out, beta, invq, wsi);
        echo_mag<<<B, TPB, 0, stream>>>(x_real, x_imag, t, trig_r, trig_i, b_query,
                                        invq, mag);
        const int nblocks = 2048;       // grid-stride, ~8 blocks/CU
        echo_proj<<<nblocks, TPB, 0, stream>>>(x_real, x_imag, t, b_out, wsi, mag,
                                               out, B, nblocks);
    } else {
        echo_single<<<B, TPB, 0, stream>>>(
            x_real, x_imag, t, trig_r, trig_i, w_query, b_query, w_out, b_out, beta,
            out, B);
    }
}

// Round 15
// 263.560 us; speedup vs baseline: 1.0497x; 1.0497x over previous
//
#include <hip/hip_runtime.h>

#define LUT_N 4096
#define DVAL  4096
#define TPB   256
#define RPB   4      // rows per persistent block

static constexpr double TWO_PI_D = 6.283185307179586476925286766559;
#define PHI_F 1.61803398874989484820f

// ---------- helpers ----------
__device__ __forceinline__ float fc(const float4& f, int j) {
    switch (j) { case 0: return f.x; case 1: return f.y; case 2: return f.z; }
    return f.w;
}
__device__ __forceinline__ void sc4(float4& f, int j, float v) {
    switch (j) { case 0: f.x = v; return; case 1: f.y = v; return; case 2: f.z = v; return; }
    f.w = v;
}
// Reference: idx = mod(round(theta*(N/2pi)), N); value = table[idx].
// Same quantization (rintf = round-half-even = jnp.round); value via HW trans ops
// (input in REVOLUTIONS): sin/cos(2*pi*fract((r+s)/4096)). |r+s| < 2^24 so the mod
// is exact; argument error <= 5e-7 << validated 0.0039 absmax.
__device__ __forceinline__ void grid_sincos(float thr, float thi, float cidx,
                                            float& s_out, float& c_out) {
    float r = rintf(thr * cidx);
    float s = rintf(thi * cidx);
    float rev = (r + s) * (1.0f / (float)LUT_N);
    float frac = rev - floorf(rev);
    s_out = __builtin_amdgcn_sinf(frac);
    c_out = __builtin_amdgcn_cosf(frac);
}

// ---------- precompute: per-column reciprocals ----------
__global__ __launch_bounds__(256) void echo_precompute(
    const float* __restrict__ w_query,
    const float* __restrict__ w_out,
    const float* __restrict__ beta,
    float* __restrict__ invq,  // [D] 1/(1+|w_query|)
    float* __restrict__ wsi)   // [D] write_scale/wavelength
{
    int i = blockIdx.x * 256 + threadIdx.x;
    if (i < DVAL) {
        float inv_q     = 1.0f / (1.0f + fabsf(w_query[i]));
        float w_eff     = 1.0f / (1.0f + fabsf(w_out[i]));
        float beta_eff  = 1.0f / (1.0f + fabsf(beta[i]));
        float decay     = fminf(expf(-beta_eff * w_eff), 0.9999f);
        invq[i] = inv_q;
        wsi[i]  = (w_eff * (1.0f - decay)) * w_eff;
    }
}

// ---------- persistent fused kernel: RPB rows per block, x double-buffered in regs ----------
template<bool USE_WS>
__global__ __launch_bounds__(TPB, 4) void echo_persist(
    const float* __restrict__ x_real,
    const float* __restrict__ x_imag,
    const float* __restrict__ t,
    const float* __restrict__ trig_r,
    const float* __restrict__ trig_i,
    const float* __restrict__ w_query,
    const float* __restrict__ b_query,
    const float* __restrict__ w_out,
    const float* __restrict__ b_out,
    const float* __restrict__ beta,
    const float* __restrict__ invqG,
    const float* __restrict__ wsiG,
    float* __restrict__ out,
    int B)
{
    __shared__ float redR[4], redI[4];
    __shared__ float magS;

    const int tid  = threadIdx.x;
    const int row0 = blockIdx.x * RPB;
    const float cidx = (float)((double)LUT_N / TWO_PI_D);  // 651.89865f

    float4 curR[4], curI[4], nxtR[4], nxtI[4];

    // prime the pipeline: load row0's x (only exposed-latency load of the whole block)
    {
        int row = min(row0, B - 1);
        const float4* xr4 = (const float4*)(x_real + (size_t)row * DVAL);
        const float4* xi4 = (const float4*)(x_imag + (size_t)row * DVAL);
        #pragma unroll
        for (int k = 0; k < 4; ++k) {
            curR[k] = xr4[tid + TPB * k];
            curI[k] = xi4[tid + TPB * k];
        }
    }

    #pragma unroll
    for (int r = 0; r < RPB; ++r) {
        const int row = min(row0 + r, B - 1);   // clamp: duplicate rows write identical data

        // ---- issue next row's x loads NOW; they complete under this row's compute ----
        if (r + 1 < RPB) {
            int nrow = min(row0 + r + 1, B - 1);
            const float4* xr4 = (const float4*)(x_real + (size_t)nrow * DVAL);
            const float4* xi4 = (const float4*)(x_imag + (size_t)nrow * DVAL);
            #pragma unroll
            for (int k = 0; k < 4; ++k) {
                nxtR[k] = xr4[tid + TPB * k];
                nxtI[k] = xi4[tid + TPB * k];
            }
        }

        const float tphi = t[row] * PHI_F;
        float accr = 0.0f, acci = 0.0f;

        // ---- stage 1: interference accumulate (x already in registers) ----
        #pragma unroll
        for (int k = 0; k < 4; ++k) {
            int v = tid + TPB * k;
            float4 iv4;
            if constexpr (USE_WS) {
                iv4 = ((const float4*)invqG)[v];
            } else {
                float4 wq4 = ((const float4*)w_query)[v];
                iv4 = make_float4(1.0f / (1.0f + fabsf(wq4.x)), 1.0f / (1.0f + fabsf(wq4.y)),
                                  1.0f / (1.0f + fabsf(wq4.z)), 1.0f / (1.0f + fabsf(wq4.w)));
            }
            float4 bq4 = ((const float4*)b_query)[v];
            float4 tr4 = ((const float4*)trig_r)[v];
            float4 ti4 = ((const float4*)trig_i)[v];

            #pragma unroll
            for (int j = 0; j < 4; ++j) {
                float iv = fc(iv4, j), bq = fc(bq4, j);
                float thr = __builtin_fmaf(fc(curR[k], j), iv, bq) + tphi;
                float thi = __builtin_fmaf(fc(curI[k], j), iv, bq) + tphi;
                float q_i, q_r;
                grid_sincos(thr, thi, cidx, q_i, q_r);
                accr = __builtin_fmaf(q_r, fc(tr4, j), __builtin_fmaf(q_i, fc(ti4, j), accr));
                acci = __builtin_fmaf(q_r, fc(ti4, j), __builtin_fmaf(-q_i, fc(tr4, j), acci));
            }
        }

        // ---- per-row reduction -> int_mag ----
        #pragma unroll
        for (int m = 32; m >= 1; m >>= 1) {
            accr += __shfl_xor(accr, m, 64);
            acci += __shfl_xor(acci, m, 64);
        }
        if ((tid & 63) == 0) { redR[tid >> 6] = accr; redI[tid >> 6] = acci; }
        __syncthreads();
        if (tid == 0) {
            float tr = (redR[0] + redR[1] + redR[2] + redR[3]) * 0.0625f;
            float ti = (redI[0] + redI[1] + redI[2] + redI[3]) * 0.0625f;
            magS = sqrtf(tr * tr + ti * ti + 1e-8f);
        }
        __syncthreads();
        const float mag = magS;

        // ---- stage 2: projection + store (x still in registers) ----
        float4* outR = (float4*)(out + (size_t)row * DVAL);
        float4* outI = (float4*)(out + (size_t)B * DVAL + (size_t)row * DVAL);

        #pragma unroll
        for (int k = 0; k < 4; ++k) {
            int v = tid + TPB * k;
            float4 ws4;
            if constexpr (USE_WS) {
                ws4 = ((const float4*)wsiG)[v];
            } else {
                float4 wo4 = ((const float4*)w_out)[v];
                float4 be4 = ((const float4*)beta)[v];
                #pragma unroll
                for (int j = 0; j < 4; ++j) {
                    float w_eff = 1.0f / (1.0f + fabsf(fc(wo4, j)));
                    float beta_eff = 1.0f / (1.0f + fabsf(fc(be4, j)));
                    float decay = fminf(expf(-beta_eff * w_eff), 0.9999f);
                    sc4(ws4, j, (w_eff * (1.0f - decay)) * w_eff);
                }
            }
            float4 bo4 = ((const float4*)b_out)[v];

            float4 oR, oI;
            #pragma unroll
            for (int j = 0; j < 4; ++j) {
                float xmr = fc(curR[k], j) * mag;
                float xmi = fc(curI[k], j) * mag;
                float thr = __builtin_fmaf(xmr, fc(ws4, j), fc(bo4, j)) + tphi;
                float thi = __builtin_fmaf(xmi, fc(ws4, j), fc(bo4, j)) + tphi;
                float s_o, c_o;
                grid_sincos(thr, thi, cidx, s_o, c_o);
                sc4(oR, j, c_o);
                sc4(oI, j, s_o);
            }
            outR[v] = oR;
            outI[v] = oI;
        }

        // ---- static swap (unrolled loop -> pure register renaming) ----
        if (r + 1 < RPB) {
            #pragma unroll
            for (int k = 0; k < 4; ++k) {
                curR[k] = nxtR[k];
                curI[k] = nxtI[k];
            }
        }
    }
}

extern "C" void kernel_launch(void* const* d_in, const int* in_sizes, int n_in,
                              void* d_out, int out_size, void* d_ws, size_t ws_size,
                              hipStream_t stream) {
    const float* x_real    = (const float*)d_in[0];
    const float* x_imag    = (const float*)d_in[1];
    const float* t         = (const float*)d_in[2];
    const float* trig_r    = (const float*)d_in[3];
    const float* trig_i    = (const float*)d_in[4];
    const float* w_query   = (const float*)d_in[5];
    const float* b_query   = (const float*)d_in[6];
    const float* w_out     = (const float*)d_in[7];
    const float* b_out     = (const float*)d_in[8];
    const float* beta      = (const float*)d_in[9];
    float* out = (float*)d_out;

    const int B = in_sizes[2];                  // 4096
    const int nblocks = (B + RPB - 1) / RPB;    // 1024 persistent blocks
    const size_t need = 2 * (size_t)DVAL * sizeof(float);

    if (d_ws != nullptr && ws_size >= need) {
        float* invq = (float*)d_ws;
        float* wsi  = invq + DVAL;
        echo_precompute<<<DVAL / 256, 256, 0, stream>>>(w_query, w_out, beta, invq, wsi);
        echo_persist<true><<<nblocks, TPB, 0, stream>>>(
            x_real, x_imag, t, trig_r, trig_i, w_query, b_query, w_out, b_out, beta,
            invq, wsi, out, B);
    } else {
        echo_persist<false><<<nblocks, TPB, 0, stream>>>(
            x_real, x_imag, t, trig_r, trig_i, w_query, b_query, w_out, b_out, beta,
            nullptr, nullptr, out, B);
    }
}